// Round 9
// baseline (710.372 us; speedup 1.0000x reference)
//
#include <hip/hip_runtime.h>

typedef unsigned short u16;
typedef unsigned int u32;

using short8 = __attribute__((ext_vector_type(8))) short;
using f32x4  = __attribute__((ext_vector_type(4))) float;

#define LOG2E 1.44269504088896340736f

// X1 row (per batch): [h1_hi 0:128 | h1_lo 128:256 | x 256:272 | zeros 272:288 | pad]
#define X1S 296
// H2 row: [h2_hi 0:64 | h2_lo 64:128 | pad]
#define H2S 136
#define DBS 40

__device__ __forceinline__ u16 f2bf(float f) {
  u32 u = __float_as_uint(f);
  return (u16)((u + 0x7FFFu + ((u >> 16) & 1u)) >> 16);
}
__device__ __forceinline__ float bf2f(u16 h) {
  return __uint_as_float(((u32)h) << 16);
}
__device__ __forceinline__ float sigm(float x) {
  return __builtin_amdgcn_rcpf(1.0f + __builtin_amdgcn_exp2f(-LOG2E * x));
}
__device__ __forceinline__ float tanh_(float x) {
  return 1.0f - 2.0f * __builtin_amdgcn_rcpf(1.0f + __builtin_amdgcn_exp2f(2.0f * LOG2E * x));
}
__device__ __forceinline__ f32x4 mfma_(short8 a, short8 b, f32x4 c) {
  return __builtin_amdgcn_mfma_f32_16x16x32_bf16(a, b, c, 0, 0, 0);
}

// 512 threads (8 waves, 2/SIMD). R9: BALANCED waves — every wave owns
// 16 L1 units (Whh1 = 64 VGPR) AND 8 L2 units via paired gate-tiles
// (tile p=0 covers {i,f} x 8 units, p=1 covers {g,o}; Whh2 = 16 VGPR).
// Per wave per step: 60 MFMA + ~6 elem rows — no straggler wave, so the
// barrier no longer serializes a 2.3x-loaded A-chain.
__global__ __launch_bounds__(512, 1) void spc_lstm(
    const float* __restrict__ xh,   const float* __restrict__ xfr,
    const float* __restrict__ Wih1, const float* __restrict__ Whh1,
    const float* __restrict__ bih1, const float* __restrict__ bhh1,
    const float* __restrict__ Wih2, const float* __restrict__ Whh2,
    const float* __restrict__ bih2, const float* __restrict__ bhh2,
    const float* __restrict__ Wd,   const float* __restrict__ bd,
    const float* __restrict__ Wf,   const float* __restrict__ bfv,
    const float* __restrict__ ob,   float* __restrict__ out)
{
  __shared__ __align__(16) u16 X1[2][16 * X1S];   // 18944 B
  __shared__ __align__(16) u16 H2B[2][16 * H2S];  //  8704 B
  __shared__ __align__(16) u16 DB[16 * DBS];      //  1280 B
  __shared__ __align__(16) u16 W1xF[32 * 256];    // 16384 B (k<16 only)
  __shared__ __align__(16) u16 W2F[64 * 512];     // 65536 B Wih2 paired tiles
  __shared__ __align__(16) u16 WdF[4 * 512];      //  4096 B
  __shared__ __align__(16) u16 WfF[512];          //  1024 B
  __shared__ u16 PREDV[16][2];
  // ~116 KB

  const int tid = threadIdx.x;
  const int wv  = tid >> 6;          // 0..7
  const int l   = tid & 63;
  const int c   = l & 15;
  const int q   = l >> 4;
  const int bb  = blockIdx.x << 4;
  const bool isA = (wv < 4);

  short8 w1h[4][4];                  // Whh1 frags, 16 L1 units (64 VGPR)
  short8 w2h[2][2];                  // Whh2 frags, 8 L2 units, paired (16 VGPR)
  float  b1r[4];
  float  b2p[2];

  // ---- zero activation LDS ----
  for (int i = tid; i < 2 * 16 * X1S; i += 512) ((u16*)X1)[i] = 0;
  for (int i = tid; i < 2 * 16 * H2S; i += 512) ((u16*)H2B)[i] = 0;
  for (int i = tid; i < 16 * DBS; i += 512) DB[i] = 0;
  if (tid < 32) ((u16*)PREDV)[tid] = 0;
  __syncthreads();

  // ---- weight LDS fills (fragment-linear: (k,n) -> ((k>>3)*16+n)*8 + (k&7)) ----
  for (int i = tid; i < 64 * 512; i += 512) {         // Wih2, paired tiles T=(ww,p,kc)
    const int rid = i >> 9, e = i & 511, k = e >> 4, n = e & 15;
    const int ww = rid >> 3, p = (rid >> 2) & 1, kc = rid & 3;
    const int g = (2 * p + (n >> 3)) * 64 + ww * 8 + (n & 7);
    W2F[rid * 512 + ((k >> 3) * 16 + n) * 8 + (k & 7)] = f2bf(Wih2[g * 128 + kc * 32 + k]);
  }
  for (int i = tid; i < 32 * 256; i += 512) {         // Wih1 x-frags, tiles T = ty*8+uv
    const int T = i >> 8, e = i & 255, k = e >> 4, n = e & 15;
    const int ty = T >> 3, uv = T & 7;
    const int g = ty * 128 + uv * 16 + n;
    W1xF[T * 256 + ((k >> 3) * 16 + n) * 8 + (k & 7)] = f2bf(Wih1[g * 16 + k]);
  }
  for (int i = tid; i < 4 * 512; i += 512) {          // Wd tiles (ww, kc2)
    const int tix = i >> 9, e = i & 511, k = e >> 4, n = e & 15;
    const int ww = tix >> 1, kc2 = tix & 1;
    WdF[tix * 512 + ((k >> 3) * 16 + n) * 8 + (k & 7)] =
        f2bf(Wd[(ww * 16 + n) * 64 + kc2 * 32 + k]);
  }
  {                                                   // Wf (zeros n>=2)
    const int k = tid >> 4, n = tid & 15;
    if (tid < 512)
      WfF[((k >> 3) * 16 + n) * 8 + (k & 7)] = (n < 2) ? f2bf(Wf[n * 32 + k]) : (u16)0;
  }

  // ---- register weights / biases ----
  #pragma unroll
  for (int ty = 0; ty < 4; ty++) {                    // L1: wave owns units wv*16+c
    const int g = ty * 128 + wv * 16 + c;
    b1r[ty] = bih1[g] + bhh1[g];
    #pragma unroll
    for (int kc = 0; kc < 4; kc++) {
      short8 v;
      #pragma unroll
      for (int j = 0; j < 8; j++)
        v[j] = (short)f2bf(Whh1[g * 128 + kc * 32 + q * 8 + j]);
      w1h[ty][kc] = v;
    }
  }
  #pragma unroll
  for (int p = 0; p < 2; p++) {                       // L2: wave owns units wv*8+(c&7)
    const int g2 = (2 * p + (c >> 3)) * 64 + wv * 8 + (c & 7);
    b2p[p] = bih2[g2] + bhh2[g2];
    #pragma unroll
    for (int kc = 0; kc < 2; kc++) {
      short8 v;
      #pragma unroll
      for (int j = 0; j < 8; j++)
        v[j] = (short)f2bf(Whh2[g2 * 64 + kc * 32 + q * 8 + j]);
      w2h[p][kc] = v;
    }
  }
  const float bdr = (wv == 4 || wv == 5) ? bd[(wv - 4) * 16 + c] : 0.f;
  const float bfr = (wv == 4 && c < 2) ? (bfv[c] + ob[c]) : 0.f;

  // ---- x staging (waves 4-7): stage x(0), prime x(1) ----
  const int xi = tid - 256, xr = (xi >> 4) & 15, xcc = xi & 15;
  float xreg = 0.f; bool dreg = false;
  if (!isA) {
    X1[0][xr * X1S + 256 + xcc] = f2bf(xh[(bb + xr) * 3200 + xcc]);
    xreg = xh[(bb + xr) * 3200 + 16 + xcc]; dreg = true;
  }
  f32x4 c1 = (f32x4){0,0,0,0};
  f32x4 c2 = (f32x4){0,0,0,0};
  __syncthreads();

  for (int t = 0; t <= 220; t++) {
    u16* Xc    = X1[t & 1];        // h1(t-1) hi/lo + x(t)
    u16* Xn    = X1[(t + 1) & 1];  // h1(t) dest, x(t+1) stage
    u16* Hprev = H2B[t & 1];       // h2(t-2)
    u16* Hdst  = H2B[(t + 1) & 1]; // h2(t-1) dest
    const bool dec  = (t >= 201);
    const bool doL1 = (t <= 219);
    const bool doL2 = (t >= 1);

    // ---- x prefetch issue (waves 4-7) ----
    float xw = 0.f; bool dw = false;
    if (!isA) {
      xw = xreg; dw = dreg;
      const int s2 = t + 2;
      dreg = false;
      if (s2 < 200) { xreg = xh[(bb + xr) * 3200 + s2 * 16 + xcc]; dreg = true; }
      else if (s2 < 220) {
        const int s = s2 - 200;
        if (xcc < 14)    { xreg = xfr[(bb + xr) * 280 + s * 14 + xcc]; dreg = true; }
        else if (s == 0) { xreg = xh[(bb + xr) * 3200 + 199 * 16 + xcc]; dreg = true; }
      }
    }

    // ==== MFMA issue phase ====
    f32x4 acc1[4]; f32x4 acc2[2];
    short8 fh[8];                      // h1(t-1) hi(0..3)/lo(4..7)
    #pragma unroll
    for (int kc = 0; kc < 4; kc++) {
      fh[kc]     = *(const short8*)&Xc[c * X1S + kc * 32 + q * 8];
      fh[4 + kc] = *(const short8*)&Xc[c * X1S + 128 + kc * 32 + q * 8];
    }
    if (doL1) {                        // L1(t) h-part (+ x-part in encoder)
      #pragma unroll
      for (int ty = 0; ty < 4; ty++)
        acc1[ty] = (f32x4){b1r[ty], b1r[ty], b1r[ty], b1r[ty]};
      #pragma unroll
      for (int kc = 0; kc < 4; kc++) {
        #pragma unroll
        for (int ty = 0; ty < 4; ty++) {
          acc1[ty] = mfma_(fh[kc],     w1h[ty][kc], acc1[ty]);
          acc1[ty] = mfma_(fh[4 + kc], w1h[ty][kc], acc1[ty]);
        }
      }
      if (t <= 200) {
        const short8 ax = *(const short8*)&Xc[c * X1S + 256 + q * 8];
        #pragma unroll
        for (int ty = 0; ty < 4; ty++) {
          short8 wxv = (short8){0,0,0,0,0,0,0,0};
          if (q < 2)
            wxv = *(const short8*)&W1xF[(ty * 8 + wv) * 256 + l * 8];
          acc1[ty] = mfma_(ax, wxv, acc1[ty]);
        }
      }
    }
    if (doL2) {                        // L2(t-1), paired tiles
      #pragma unroll
      for (int p = 0; p < 2; p++)
        acc2[p] = (f32x4){b2p[p], b2p[p], b2p[p], b2p[p]};
      #pragma unroll
      for (int kc = 0; kc < 4; kc++) {
        #pragma unroll
        for (int p = 0; p < 2; p++) {
          const short8 wf_ = *(const short8*)&W2F[(wv * 8 + p * 4 + kc) * 512 + l * 8];
          acc2[p] = mfma_(fh[kc],     wf_, acc2[p]);
          acc2[p] = mfma_(fh[4 + kc], wf_, acc2[p]);
        }
      }
      #pragma unroll
      for (int kc = 0; kc < 2; kc++) {
        const short8 hhi = *(const short8*)&Hprev[c * H2S + kc * 32 + q * 8];
        const short8 hlo = *(const short8*)&Hprev[c * H2S + 64 + kc * 32 + q * 8];
        #pragma unroll
        for (int p = 0; p < 2; p++) {
          acc2[p] = mfma_(hhi, w2h[p][kc], acc2[p]);
          acc2[p] = mfma_(hlo, w2h[p][kc], acc2[p]);
        }
      }
    }

    if (!isA && dw) Xn[xr * X1S + 256 + xcc] = f2bf(xw);   // stage x(t+1)

    // ==== elem phase ====
    // L2 elem: lanes c and c+8 hold {i,f}/{g,o} of the same unit; pair via shfl.
    if (!dec) {
      if (doL1) {                      // L1 elem -> h1(t)
        const int u = wv * 16 + c;
        #pragma unroll
        for (int r = 0; r < 4; r++) {
          float ig = sigm(acc1[0][r]);
          float fg = sigm(acc1[1][r]);
          float gg = tanh_(acc1[2][r]);
          float og = sigm(acc1[3][r]);
          float cn = fg * c1[r] + ig * gg;
          float hn = og * tanh_(cn);
          c1[r] = cn;
          u16 hi = f2bf(hn);
          float lo = hn - bf2f(hi);
          const int row = (q * 4 + r) * X1S;
          Xn[row + u]       = hi;
          Xn[row + 128 + u] = f2bf(lo);
        }
      }
      if (doL2) {                      // L2 elem -> h2(t-1)
        const int u2 = wv * 8 + (c & 7);
        #pragma unroll
        for (int r = 0; r < 4; r++) {
          const float pf = __shfl_xor(acc2[0][r], 8);
          const float po = __shfl_xor(acc2[1][r], 8);
          if (c < 8) {
            float ig = sigm(acc2[0][r]);
            float fg = sigm(pf);
            float gg = tanh_(acc2[1][r]);
            float og = sigm(po);
            float cn = fg * c2[r] + ig * gg;
            float hn = og * tanh_(cn);
            c2[r] = cn;
            u16 hi = f2bf(hn);
            float lo = hn - bf2f(hi);
            const int row = (q * 4 + r) * H2S;
            Hdst[row + u2]      = hi;
            Hdst[row + 64 + u2] = f2bf(lo);
          }
        }
      }
      __syncthreads();                 // publish h1(t), h2(t-1), x(t+1)
    } else {
      if (doL2) {                      // L2 elem first (head needs h2(t-1))
        const int u2 = wv * 8 + (c & 7);
        #pragma unroll
        for (int r = 0; r < 4; r++) {
          const float pf = __shfl_xor(acc2[0][r], 8);
          const float po = __shfl_xor(acc2[1][r], 8);
          if (c < 8) {
            float ig = sigm(acc2[0][r]);
            float fg = sigm(pf);
            float gg = tanh_(acc2[1][r]);
            float og = sigm(po);
            float cn = fg * c2[r] + ig * gg;
            float hn = og * tanh_(cn);
            c2[r] = cn;
            u16 hi = f2bf(hn);
            float lo = hn - bf2f(hi);
            const int row = (q * 4 + r) * H2S;
            Hdst[row + u2]      = hi;
            Hdst[row + 64 + u2] = f2bf(lo);
          }
        }
      }
      __syncthreads();                 // #1: h2(t-1) visible
      if (wv == 4 || wv == 5) {
        const int ww = wv - 4;
        f32x4 accd = (f32x4){bdr, bdr, bdr, bdr};
        #pragma unroll
        for (int kc = 0; kc < 4; kc++) {
          const short8 ad  = *(const short8*)&Hdst[c * H2S + kc * 32 + q * 8];
          const short8 wdk = *(const short8*)&WdF[(ww * 2 + (kc & 1)) * 512 + l * 8];
          accd = mfma_(ad, wdk, accd);
        }
        #pragma unroll
        for (int r = 0; r < 4; r++)
          DB[(q * 4 + r) * DBS + ww * 16 + c] = f2bf(fmaxf(accd[r], 0.f));
      }
      __syncthreads();                 // #2: d visible
      if (wv == 4) {
        const short8 ap  = *(const short8*)&DB[c * DBS + q * 8];
        const short8 wfv = *(const short8*)&WfF[l * 8];
        f32x4 accp = (f32x4){bfr, bfr, bfr, bfr};
        accp = mfma_(ap, wfv, accp);
        if (c < 2) {
          #pragma unroll
          for (int r = 0; r < 4; r++) {
            const int b = q * 4 + r;
            out[(bb + b) * 40 + (t - 201) * 2 + c] = accp[r];
            PREDV[b][c] = f2bf(accp[r]);
          }
        }
      }
      __syncthreads();                 // #3: pred visible
      if (doL1) {                      // deferred x-part + L1 elem
        short8 ax = *(const short8*)&Xc[c * X1S + 256 + q * 8];
        if (q == 1) {
          ax[6] = (short)PREDV[c][0];
          ax[7] = (short)PREDV[c][1];
        }
        #pragma unroll
        for (int ty = 0; ty < 4; ty++) {
          short8 wxv = (short8){0,0,0,0,0,0,0,0};
          if (q < 2)
            wxv = *(const short8*)&W1xF[(ty * 8 + wv) * 256 + l * 8];
          acc1[ty] = mfma_(ax, wxv, acc1[ty]);
        }
        const int u = wv * 16 + c;
        #pragma unroll
        for (int r = 0; r < 4; r++) {
          float ig = sigm(acc1[0][r]);
          float fg = sigm(acc1[1][r]);
          float gg = tanh_(acc1[2][r]);
          float og = sigm(acc1[3][r]);
          float cn = fg * c1[r] + ig * gg;
          float hn = og * tanh_(cn);
          c1[r] = cn;
          u16 hi = f2bf(hn);
          float lo = hn - bf2f(hi);
          const int row = (q * 4 + r) * X1S;
          Xn[row + u]       = hi;
          Xn[row + 128 + u] = f2bf(lo);
        }
      }
      __syncthreads();                 // #4: h1(t) published
    }
  }
}

extern "C" void kernel_launch(void* const* d_in, const int* in_sizes, int n_in,
                              void* d_out, int out_size, void* d_ws, size_t ws_size,
                              hipStream_t stream) {
  (void)in_sizes; (void)n_in; (void)out_size; (void)d_ws; (void)ws_size;
  spc_lstm<<<dim3(256), dim3(512), 0, stream>>>(
      (const float*)d_in[0],  (const float*)d_in[1],
      (const float*)d_in[2],  (const float*)d_in[3],
      (const float*)d_in[4],  (const float*)d_in[5],
      (const float*)d_in[6],  (const float*)d_in[7],
      (const float*)d_in[8],  (const float*)d_in[9],
      (const float*)d_in[10], (const float*)d_in[11],
      (const float*)d_in[12], (const float*)d_in[13],
      (const float*)d_in[14], (float*)d_out);
}

// Round 10
// 622.661 us; speedup vs baseline: 1.1409x; 1.1409x over previous
//
#include <hip/hip_runtime.h>

typedef unsigned short u16;
typedef unsigned int u32;

using short8 = __attribute__((ext_vector_type(8))) short;
using f32x4  = __attribute__((ext_vector_type(4))) float;

#define LOG2E 1.44269504088896340736f

// X1 row (per batch): [h1_hi 0:128 | h1_lo 128:256 | x 256:272 | zeros 272:288 | pad]
#define X1S 296
// H2 row: [h2_hi 0:64 | h2_lo 64:128 | pad]
#define H2S 136
#define DBS 40

__device__ __forceinline__ u16 f2bf(float f) {
  u32 u = __float_as_uint(f);
  return (u16)((u + 0x7FFFu + ((u >> 16) & 1u)) >> 16);
}
__device__ __forceinline__ float bf2f(u16 h) {
  return __uint_as_float(((u32)h) << 16);
}
__device__ __forceinline__ float sigm(float x) {
  return __builtin_amdgcn_rcpf(1.0f + __builtin_amdgcn_exp2f(-LOG2E * x));
}
__device__ __forceinline__ float tanh_(float x) {
  return 1.0f - 2.0f * __builtin_amdgcn_rcpf(1.0f + __builtin_amdgcn_exp2f(2.0f * LOG2E * x));
}
__device__ __forceinline__ f32x4 mfma_(short8 a, short8 b, f32x4 c) {
  return __builtin_amdgcn_mfma_f32_16x16x32_bf16(a, b, c, 0, 0, 0);
}

// 768 threads = 12 waves (3/SIMD: 2 L1-waves + 1 L2-wave, wave->SIMD = id%4).
// De-phased schedule: phase1 = A-elem (VALU) || B-MFMA (matrix pipe);
// phase2 = A-MFMA || B-elem+staging. MFMA drain of one group overlaps VALU
// of the other (m114 co-scheduling), targeting the measured 85% issue-sum.
__global__ __launch_bounds__(768, 1) void spc_lstm(
    const float* __restrict__ xh,   const float* __restrict__ xfr,
    const float* __restrict__ Wih1, const float* __restrict__ Whh1,
    const float* __restrict__ bih1, const float* __restrict__ bhh1,
    const float* __restrict__ Wih2, const float* __restrict__ Whh2,
    const float* __restrict__ bih2, const float* __restrict__ bhh2,
    const float* __restrict__ Wd,   const float* __restrict__ bd,
    const float* __restrict__ Wf,   const float* __restrict__ bfv,
    const float* __restrict__ ob,   float* __restrict__ out)
{
  __shared__ __align__(16) u16 X1[2][16 * X1S];   // 18944 B
  __shared__ __align__(16) u16 H2B[2][16 * H2S];  //  8704 B
  __shared__ __align__(16) u16 DB[16 * DBS];      //  1280 B
  __shared__ __align__(16) u16 W1xF[32 * 256];    // 16384 B Wih1 x-frags
  __shared__ __align__(16) u16 W2F[64 * 512];     // 65536 B Wih2 frags
  __shared__ __align__(16) u16 WdF[4 * 512];      //  4096 B
  __shared__ __align__(16) u16 WfF[512];          //  1024 B
  __shared__ u16 PREDV[16][2];
  // total ~113.3 KB

  const int tid = threadIdx.x;
  const int wv  = tid >> 6;          // 0..11
  const int l   = tid & 63;
  const int c   = l & 15;
  const int q   = l >> 4;
  const int bb  = blockIdx.x << 4;
  const bool isA = (wv < 8);         // waves 0-7: L1; waves 8-11: L2 + head + x
  const int wb  = wv - 8;

  // role-overlaid registers (union kept small: ~125 peak)
  short8 wreg[4][4];   // A: Whh1 frags (64); B: Whh2 frags in [ty][0..1]
  float  br[4];        // A: b1; B: b2
  f32x4  acc[4];       // A: L1 preacts; B: L2 preacts (held across barriers)
  f32x4  cst = (f32x4){0, 0, 0, 0};   // c1 / c2

  // ---- zero activation LDS ----
  for (int i = tid; i < 2 * 16 * X1S; i += 768) ((u16*)X1)[i] = 0;
  for (int i = tid; i < 2 * 16 * H2S; i += 768) ((u16*)H2B)[i] = 0;
  for (int i = tid; i < 16 * DBS; i += 768) DB[i] = 0;
  if (tid < 32) ((u16*)PREDV)[tid] = 0;
  __syncthreads();

  // ---- weight LDS fills (fragment-linear: (k,n) -> ((k>>3)*16+n)*8 + (k&7)) ----
  for (int i = tid; i < 64 * 512; i += 768) {         // Wih2 tiles (wb, ty, kc)
    const int rid = i >> 9, e = i & 511, k = e >> 4, n = e & 15;
    const int ww = rid >> 4, ty = (rid >> 2) & 3, kc = rid & 3;
    const int g = ty * 64 + ww * 16 + n;
    W2F[rid * 512 + ((k >> 3) * 16 + n) * 8 + (k & 7)] = f2bf(Wih2[g * 128 + kc * 32 + k]);
  }
  for (int i = tid; i < 32 * 256; i += 768) {         // Wih1 x-frags, tiles T = ty*8+uv
    const int T = i >> 8, e = i & 255, k = e >> 4, n = e & 15;
    const int ty = T >> 3, uv = T & 7;
    const int g = ty * 128 + uv * 16 + n;
    W1xF[T * 256 + ((k >> 3) * 16 + n) * 8 + (k & 7)] = f2bf(Wih1[g * 16 + k]);
  }
  for (int i = tid; i < 4 * 512; i += 768) {          // Wd tiles (ww, kc2)
    const int tix = i >> 9, e = i & 511, k = e >> 4, n = e & 15;
    const int ww = tix >> 1, kc2 = tix & 1;
    WdF[tix * 512 + ((k >> 3) * 16 + n) * 8 + (k & 7)] =
        f2bf(Wd[(ww * 16 + n) * 64 + kc2 * 32 + k]);
  }
  for (int i = tid; i < 512; i += 768) {              // Wf (zeros n>=2)
    const int k = i >> 4, n = i & 15;
    WfF[((k >> 3) * 16 + n) * 8 + (k & 7)] = (n < 2) ? f2bf(Wf[n * 32 + k]) : (u16)0;
  }

  // ---- register weights / biases ----
  if (isA) {
    #pragma unroll
    for (int ty = 0; ty < 4; ty++) {                  // L1 units wv*16+c
      const int g = ty * 128 + wv * 16 + c;
      br[ty] = bih1[g] + bhh1[g];
      #pragma unroll
      for (int kc = 0; kc < 4; kc++) {
        short8 v;
        #pragma unroll
        for (int j = 0; j < 8; j++)
          v[j] = (short)f2bf(Whh1[g * 128 + kc * 32 + q * 8 + j]);
        wreg[ty][kc] = v;
      }
    }
  } else {
    #pragma unroll
    for (int ty = 0; ty < 4; ty++) {                  // L2 units wb*16+c
      const int g2 = ty * 64 + wb * 16 + c;
      br[ty] = bih2[g2] + bhh2[g2];
      #pragma unroll
      for (int kc = 0; kc < 2; kc++) {
        short8 v;
        #pragma unroll
        for (int j = 0; j < 8; j++)
          v[j] = (short)f2bf(Whh2[g2 * 64 + kc * 32 + q * 8 + j]);
        wreg[ty][kc] = v;
      }
      wreg[ty][2] = (short8){0,0,0,0,0,0,0,0};
      wreg[ty][3] = (short8){0,0,0,0,0,0,0,0};
    }
  }
  const float bdr = (!isA && wb < 2) ? bd[wb * 16 + c] : 0.f;
  const float bfr = (!isA && wb == 0 && c < 2) ? (bfv[c] + ob[c]) : 0.f;

  // ---- x staging (B waves, 256 threads): stage x(0), prime x(1) ----
  const int xr = (tid >> 4) & 15, xcc = tid & 15;
  float xreg = 0.f; bool dreg = false;
  if (!isA) {
    X1[0][xr * X1S + 256 + xcc] = f2bf(xh[(bb + xr) * 3200 + xcc]);
    xreg = xh[(bb + xr) * 3200 + 16 + xcc]; dreg = true;
  }
  __syncthreads();

  // ---- role lambdas (numerics identical to R7 per-acc order) ----
  auto issueL1 = [&](const u16* Xsrc, bool withX) {
    #pragma unroll
    for (int ty = 0; ty < 4; ty++)
      acc[ty] = (f32x4){br[ty], br[ty], br[ty], br[ty]};
    #pragma unroll
    for (int kc = 0; kc < 4; kc++) {
      const short8 fhi = *(const short8*)&Xsrc[c * X1S + kc * 32 + q * 8];
      const short8 flo = *(const short8*)&Xsrc[c * X1S + 128 + kc * 32 + q * 8];
      #pragma unroll
      for (int ty = 0; ty < 4; ty++) {
        acc[ty] = mfma_(fhi, wreg[ty][kc], acc[ty]);
        acc[ty] = mfma_(flo, wreg[ty][kc], acc[ty]);
      }
    }
    if (withX) {
      const short8 ax = *(const short8*)&Xsrc[c * X1S + 256 + q * 8];
      #pragma unroll
      for (int ty = 0; ty < 4; ty++) {
        short8 wxv = (short8){0,0,0,0,0,0,0,0};
        if (q < 2) wxv = *(const short8*)&W1xF[(ty * 8 + wv) * 256 + l * 8];
        acc[ty] = mfma_(ax, wxv, acc[ty]);
      }
    }
  };
  auto xpatch = [&](const u16* Xsrc) {     // decode deferred x-part (+pred)
    short8 ax = *(const short8*)&Xsrc[c * X1S + 256 + q * 8];
    if (q == 1) { ax[6] = (short)PREDV[c][0]; ax[7] = (short)PREDV[c][1]; }
    #pragma unroll
    for (int ty = 0; ty < 4; ty++) {
      short8 wxv = (short8){0,0,0,0,0,0,0,0};
      if (q < 2) wxv = *(const short8*)&W1xF[(ty * 8 + wv) * 256 + l * 8];
      acc[ty] = mfma_(ax, wxv, acc[ty]);
    }
  };
  auto elemL1 = [&](u16* Xdst) {
    const int u = wv * 16 + c;
    #pragma unroll
    for (int r = 0; r < 4; r++) {
      float ig = sigm(acc[0][r]);
      float fg = sigm(acc[1][r]);
      float gg = tanh_(acc[2][r]);
      float og = sigm(acc[3][r]);
      float cn = fg * cst[r] + ig * gg;
      float hn = og * tanh_(cn);
      cst[r] = cn;
      u16 hi = f2bf(hn);
      float lo = hn - bf2f(hi);
      const int row = (q * 4 + r) * X1S;
      Xdst[row + u]       = hi;
      Xdst[row + 128 + u] = f2bf(lo);
    }
  };
  auto issueL2 = [&](const u16* Xsrc, const u16* Hsrc) {
    #pragma unroll
    for (int ty = 0; ty < 4; ty++)
      acc[ty] = (f32x4){br[ty], br[ty], br[ty], br[ty]};
    #pragma unroll
    for (int kc = 0; kc < 4; kc++) {
      const short8 fhi = *(const short8*)&Xsrc[c * X1S + kc * 32 + q * 8];
      const short8 flo = *(const short8*)&Xsrc[c * X1S + 128 + kc * 32 + q * 8];
      #pragma unroll
      for (int ty = 0; ty < 4; ty++) {
        const short8 wf_ = *(const short8*)&W2F[(wb * 16 + ty * 4 + kc) * 512 + l * 8];
        acc[ty] = mfma_(fhi, wf_, acc[ty]);
        acc[ty] = mfma_(flo, wf_, acc[ty]);
      }
    }
    #pragma unroll
    for (int kc = 0; kc < 2; kc++) {
      const short8 hhi = *(const short8*)&Hsrc[c * H2S + kc * 32 + q * 8];
      const short8 hlo = *(const short8*)&Hsrc[c * H2S + 64 + kc * 32 + q * 8];
      #pragma unroll
      for (int ty = 0; ty < 4; ty++) {
        acc[ty] = mfma_(hhi, wreg[ty][kc], acc[ty]);
        acc[ty] = mfma_(hlo, wreg[ty][kc], acc[ty]);
      }
    }
  };
  auto elemL2 = [&](u16* Hdst) {
    const int u2 = wb * 16 + c;
    #pragma unroll
    for (int r = 0; r < 4; r++) {
      float ig = sigm(acc[0][r]);
      float fg = sigm(acc[1][r]);
      float gg = tanh_(acc[2][r]);
      float og = sigm(acc[3][r]);
      float cn = fg * cst[r] + ig * gg;
      float hn = og * tanh_(cn);
      cst[r] = cn;
      u16 hi = f2bf(hn);
      float lo = hn - bf2f(hi);
      const int row = (q * 4 + r) * H2S;
      Hdst[row + u2]      = hi;
      Hdst[row + 64 + u2] = f2bf(lo);
    }
  };
  auto stagex = [&](int k, u16* Xp) {
    const float xw = xreg; const bool dw = dreg;
    const int s2 = k + 2;
    dreg = false;
    if (s2 < 200) { xreg = xh[(bb + xr) * 3200 + s2 * 16 + xcc]; dreg = true; }
    else if (s2 < 220) {
      const int s = s2 - 200;
      if (xcc < 14)    { xreg = xfr[(bb + xr) * 280 + s * 14 + xcc]; dreg = true; }
      else if (s == 0) { xreg = xh[(bb + xr) * 3200 + 199 * 16 + xcc]; dreg = true; }
    }
    if (dw) Xp[xr * X1S + 256 + xcc] = f2bf(xw);
  };
  auto headD = [&](const u16* Hsrc) {      // waves 8,9
    f32x4 accd = (f32x4){bdr, bdr, bdr, bdr};
    #pragma unroll
    for (int kc = 0; kc < 4; kc++) {
      const short8 ad  = *(const short8*)&Hsrc[c * H2S + kc * 32 + q * 8];
      const short8 wdk = *(const short8*)&WdF[(wb * 2 + (kc & 1)) * 512 + l * 8];
      accd = mfma_(ad, wdk, accd);
    }
    #pragma unroll
    for (int r = 0; r < 4; r++)
      DB[(q * 4 + r) * DBS + wb * 16 + c] = f2bf(fmaxf(accd[r], 0.f));
  };
  auto headP = [&](int s) {                // wave 8
    const short8 ap  = *(const short8*)&DB[c * DBS + q * 8];
    const short8 wfv = *(const short8*)&WfF[l * 8];
    f32x4 accp = (f32x4){bfr, bfr, bfr, bfr};
    accp = mfma_(ap, wfv, accp);
    if (c < 2) {
      #pragma unroll
      for (int r = 0; r < 4; r++) {
        const int b = q * 4 + r;
        out[(bb + b) * 40 + s * 2 + c] = accp[r];
        PREDV[b][c] = f2bf(accp[r]);
      }
    }
  };

  // ==== interval loop ====
  // invariants at interval k: A.acc = L1 preacts(k-1); (enc) B issues+consumes
  // L2 preacts(k-2) within the interval; (dec) B.acc = L2 preacts(k-2).
  for (int k = 0; k <= 221; k++) {
    u16* Xk = X1[k & 1];          // h1(k-1) dest/src; x(k)
    u16* Xp = X1[(k + 1) & 1];    // h1(k-2) [M_B enc]; x(k+1) stage; x(k-1) [dec patch]
    u16* Hk = H2B[k & 1];         // h2(k-2) dest/src
    u16* Hp = H2B[(k + 1) & 1];   // h2(k-3) [M_B enc]

    if (k <= 201) {
      // ---------- encoder interval: [A-elem || B-MFMA] ; [A-MFMA || B-elem] ----------
      if (isA) { if (k >= 1) elemL1(Xk); }            // h1(k-1)
      else     { if (k >= 2) issueL2(Xp, Hp); }       // preacts L2(k-2)
      __syncthreads();
      if (isA) { issueL1(Xk, k <= 200); }             // preacts L1(k) (x deferred at k=201)
      else     { if (k >= 2) elemL2(Hk); stagex(k, Xp); }   // h2(k-2); x(k+1)
      __syncthreads();
      if (k == 201) {                                 // transition: pipeline B across barrier
        if (!isA) issueL2(Xk, Hk);                    // preacts L2(200)
        __syncthreads();
      }
    } else {
      // ---------- decode interval (k in [202,221]) ----------
      if (!isA) elemL2(Hk);                           // h2(k-2)
      __syncthreads();
      if (!isA && wb < 2) headD(Hk);                  // d = relu(Wd@h2)
      __syncthreads();
      if (!isA && wb == 0) headP(k - 202);            // pred -> out + PREDV
      __syncthreads();
      if (isA && k <= 220) { xpatch(Xp); elemL1(Xk); }  // finish preacts(k-1); h1(k-1)
      __syncthreads();
      if (isA) { if (k <= 219) issueL1(Xk, false); }  // preacts L1(k), x deferred
      else     { if (k <= 220) issueL2(Xk, Hk); stagex(k, Xp); }  // preacts L2(k-1)
      __syncthreads();
    }
  }
}

extern "C" void kernel_launch(void* const* d_in, const int* in_sizes, int n_in,
                              void* d_out, int out_size, void* d_ws, size_t ws_size,
                              hipStream_t stream) {
  (void)in_sizes; (void)n_in; (void)out_size; (void)d_ws; (void)ws_size;
  spc_lstm<<<dim3(256), dim3(768), 0, stream>>>(
      (const float*)d_in[0],  (const float*)d_in[1],
      (const float*)d_in[2],  (const float*)d_in[3],
      (const float*)d_in[4],  (const float*)d_in[5],
      (const float*)d_in[6],  (const float*)d_in[7],
      (const float*)d_in[8],  (const float*)d_in[9],
      (const float*)d_in[10], (const float*)d_in[11],
      (const float*)d_in[12], (const float*)d_in[13],
      (const float*)d_in[14], (float*)d_out);
}